// Round 4
// baseline (258.878 us; speedup 1.0000x reference)
//
#include <hip/hip_runtime.h>
#include <hip/hip_bf16.h>

typedef __bf16 bf16;
typedef __bf16 bf16x8 __attribute__((ext_vector_type(8)));
typedef float  f32x4  __attribute__((ext_vector_type(4)));

#define NEG_BIG (-1e30f)

// load 8 contiguous f32, round to bf16x8 (two dwordx4 loads + pack)
__device__ __forceinline__ bf16x8 cvt8(const float* __restrict__ p) {
    bf16x8 r;
#pragma unroll
    for (int i = 0; i < 8; ++i) r[i] = (bf16)p[i];
    return r;
}

// ---------------------------------------------------------------------------
// Fused QKV projection: y = x @ W.T + b  (x, W, b are f32; y stored bf16).
// Tile 128x128, BK=32, 4 waves, 4x4 mfma_f32_16x16x32_bf16 each.
// Epilogue scatters to [B,H,S,D]; Q gets *1/sqrt(D) folded in.
// ---------------------------------------------------------------------------
__global__ __launch_bounds__(256) void qkv_gemm(
    const float* __restrict__ X,
    const float* __restrict__ Wq, const float* __restrict__ Wk, const float* __restrict__ Wv,
    const float* __restrict__ bq, const float* __restrict__ bk, const float* __restrict__ bv,
    bf16* __restrict__ qo, bf16* __restrict__ ko, bf16* __restrict__ vo)
{
    __shared__ alignas(16) bf16 As[128 * 40];   // row stride 40 elems (80 B)
    __shared__ alignas(16) bf16 Bs[128 * 40];

    const int t    = threadIdx.x;
    const int lane = t & 63, w = t >> 6;
    const int quad = lane >> 4, col = lane & 15;
    const int nt = blockIdx.x;            // 0..23  (3 regions x 8 n-tiles)
    const int mt = blockIdx.y;            // 0..31
    const int region = nt >> 3;           // 0=q 1=k 2=v
    const int n0 = (nt & 7) * 128;
    const int m0 = mt * 128;
    const int K  = 1024;

    const float* W    = region == 0 ? Wq : (region == 1 ? Wk : Wv);
    const float* bias = region == 0 ? bq : (region == 1 ? bk : bv);
    bf16*        out  = region == 0 ? qo : (region == 1 ? ko : vo);
    const float scale = region == 0 ? 0.125f : 1.0f;   // 1/sqrt(64)

    const int wm = (w >> 1) * 64, wn = (w & 1) * 64;
    const int r0 = t >> 2, c8 = (t & 3) * 8;   // 64 rows x 4 col-chunks / 256 thr
    f32x4 acc[4][4] = {};

    for (int k0 = 0; k0 < K; k0 += 32) {
        bf16x8 ax0 = cvt8(X + (size_t)(m0 + r0)      * K + k0 + c8);
        bf16x8 ax1 = cvt8(X + (size_t)(m0 + 64 + r0) * K + k0 + c8);
        bf16x8 bx0 = cvt8(W + (size_t)(n0 + r0)      * K + k0 + c8);
        bf16x8 bx1 = cvt8(W + (size_t)(n0 + 64 + r0) * K + k0 + c8);
        __syncthreads();                       // prev iteration's LDS reads done
        *(bf16x8*)(As + r0 * 40 + c8)        = ax0;
        *(bf16x8*)(As + (64 + r0) * 40 + c8) = ax1;
        *(bf16x8*)(Bs + r0 * 40 + c8)        = bx0;
        *(bf16x8*)(Bs + (64 + r0) * 40 + c8) = bx1;
        __syncthreads();

        bf16x8 a[4], b[4];
#pragma unroll
        for (int i = 0; i < 4; ++i)
            a[i] = *(const bf16x8*)(As + (wm + i * 16 + col) * 40 + quad * 8);
#pragma unroll
        for (int j = 0; j < 4; ++j)
            b[j] = *(const bf16x8*)(Bs + (wn + j * 16 + col) * 40 + quad * 8);
#pragma unroll
        for (int i = 0; i < 4; ++i)
#pragma unroll
            for (int j = 0; j < 4; ++j)
                acc[i][j] = __builtin_amdgcn_mfma_f32_16x16x32_bf16(a[i], b[j], acc[i][j], 0, 0, 0);
    }

    // C/D: col = lane&15, row = quad*4 + r   (m89-verified)
#pragma unroll
    for (int i = 0; i < 4; ++i) {
        const int mbase = m0 + wm + i * 16 + quad * 4;
#pragma unroll
        for (int j = 0; j < 4; ++j) {
            const int n = n0 + wn + j * 16 + col;
            const float bb = bias[n];
            const int h = n >> 6, d = n & 63;
#pragma unroll
            for (int r = 0; r < 4; ++r) {
                const int m  = mbase + r;
                const int b_ = m >> 11, s = m & 2047;
                out[(((size_t)(b_ * 16 + h)) * 2048 + s) * 64 + d] =
                    (bf16)((acc[i][j][r] + bb) * scale);
            }
        }
    }
}

// ---------------------------------------------------------------------------
// Flash attention with ALiBi + causal. One block = one (b,h) x 128-row Q tile.
// 4 waves split Q rows (32 each). KV tiles of 128. q/k/v are bf16 (ws).
// Ks [128][72], Vt transposed [64][136], Ps per-wave [32][136] (private).
// ---------------------------------------------------------------------------
__global__ __launch_bounds__(256) void attn_kernel(
    const bf16* __restrict__ Q, const bf16* __restrict__ Kg,
    const bf16* __restrict__ Vg, bf16* __restrict__ O)
{
    const int t    = threadIdx.x;
    const int lane = t & 63, w = t >> 6;
    const int quad = lane >> 4, col = lane & 15;
    const int bh = blockIdx.x & 31;
    const int qt = 15 - (blockIdx.x >> 5);    // biggest tiles dispatched first
    const int b  = bh >> 4, h = bh & 15;
    const int q0 = qt * 128;
    const float nslope = -exp2f(-0.5f * (float)(h + 1));  // H=16 slopes

    const bf16* qp = Q  + (size_t)bh * 2048 * 64;
    const bf16* kp = Kg + (size_t)bh * 2048 * 64;
    const bf16* vp = Vg + (size_t)bh * 2048 * 64;

    __shared__ alignas(16) bf16 Ks[128 * 72];
    __shared__ alignas(16) bf16 Vt[64 * 136];
    __shared__ alignas(16) bf16 Ps[4 * 32 * 136];
    bf16* Pw = Ps + w * (32 * 136);

    // Q fragments in registers all kernel: A[m=lane&15][k=quad*8+j]
    bf16x8 qa[2][2];
#pragma unroll
    for (int mi = 0; mi < 2; ++mi)
#pragma unroll
        for (int ks = 0; ks < 2; ++ks)
            qa[mi][ks] = *(const bf16x8*)(qp + (size_t)(q0 + w * 32 + mi * 16 + col) * 64
                                          + ks * 32 + quad * 8);

    float mrow[2][4], lrow[2][4];
    f32x4 of[2][4] = {};
#pragma unroll
    for (int mi = 0; mi < 2; ++mi)
#pragma unroll
        for (int r = 0; r < 4; ++r) { mrow[mi][r] = NEG_BIG; lrow[mi][r] = 0.f; }

    for (int kvt = 0; kvt <= qt; ++kvt) {
        const int kv0 = kvt * 128;

        bf16x8 kx[4], va[2], vb_[2];
#pragma unroll
        for (int i = 0; i < 4; ++i) {
            int c = i * 256 + t;               // kv = c>>3, chunk (c&7)*8
            kx[i] = *(const bf16x8*)(kp + (size_t)(kv0 + (c >> 3)) * 64 + (c & 7) * 8);
        }
#pragma unroll
        for (int i = 0; i < 2; ++i) {
            int c = i * 256 + t;               // kv-pair = c>>3, d-chunk (c&7)*8
            va[i]  = *(const bf16x8*)(vp + (size_t)(kv0 + (c >> 3) * 2)     * 64 + (c & 7) * 8);
            vb_[i] = *(const bf16x8*)(vp + (size_t)(kv0 + (c >> 3) * 2 + 1) * 64 + (c & 7) * 8);
        }
        __syncthreads();                       // prev iteration's Ks/Vt reads done
#pragma unroll
        for (int i = 0; i < 4; ++i) {
            int c = i * 256 + t;
            *(bf16x8*)(Ks + (c >> 3) * 72 + (c & 7) * 8) = kx[i];
        }
#pragma unroll
        for (int i = 0; i < 2; ++i) {
            int c = i * 256 + t;
            int kvp = c >> 3, dc = (c & 7) * 8;
#pragma unroll
            for (int e = 0; e < 8; ++e) {
                Vt[(dc + e) * 136 + kvp * 2]     = va[i][e];
                Vt[(dc + e) * 136 + kvp * 2 + 1] = vb_[i][e];
            }
        }
        __syncthreads();

        // S = Q K^T   (D=64 -> 2 mfma steps per 16x16 tile)
        f32x4 sc[2][8];
#pragma unroll
        for (int nj = 0; nj < 8; ++nj) {
            bf16x8 k0f = *(const bf16x8*)(Ks + (nj * 16 + col) * 72 + quad * 8);
            bf16x8 k1f = *(const bf16x8*)(Ks + (nj * 16 + col) * 72 + 32 + quad * 8);
#pragma unroll
            for (int mi = 0; mi < 2; ++mi) {
                f32x4 z = {};
                z = __builtin_amdgcn_mfma_f32_16x16x32_bf16(qa[mi][0], k0f, z, 0, 0, 0);
                z = __builtin_amdgcn_mfma_f32_16x16x32_bf16(qa[mi][1], k1f, z, 0, 0, 0);
                sc[mi][nj] = z;
            }
        }

        const bool diag = (kvt == qt);
        // ALiBi + causal + online softmax (finite sentinels; p overwrites sc)
#pragma unroll
        for (int mi = 0; mi < 2; ++mi) {
#pragma unroll
            for (int r = 0; r < 4; ++r) {
                const int gi = q0 + w * 32 + mi * 16 + quad * 4 + r;
                float mx = NEG_BIG;
#pragma unroll
                for (int nj = 0; nj < 8; ++nj) {
                    const int gj = kv0 + nj * 16 + col;
                    float val = sc[mi][nj][r] + nslope * (float)(gi - gj);
                    if (diag && gj > gi) val = NEG_BIG;
                    sc[mi][nj][r] = val;
                    mx = fmaxf(mx, val);
                }
#pragma unroll
                for (int off = 1; off < 16; off <<= 1)
                    mx = fmaxf(mx, __shfl_xor(mx, off, 16));
                const float mo = mrow[mi][r];
                const float mn = fmaxf(mo, mx);
                const float alpha = __expf(mo - mn);   // exp(-huge)=0, never NaN
                float rs = 0.f;
#pragma unroll
                for (int nj = 0; nj < 8; ++nj) {
                    float p = __expf(sc[mi][nj][r] - mn);
                    sc[mi][nj][r] = p;
                    rs += p;
                }
#pragma unroll
                for (int off = 1; off < 16; off <<= 1)
                    rs += __shfl_xor(rs, off, 16);
                mrow[mi][r] = mn;
                lrow[mi][r] = lrow[mi][r] * alpha + rs;
#pragma unroll
                for (int jd = 0; jd < 4; ++jd) of[mi][jd][r] *= alpha;
            }
        }

        // P: C/D layout -> A-operand layout via per-wave private LDS (no barrier)
#pragma unroll
        for (int mi = 0; mi < 2; ++mi)
#pragma unroll
            for (int nj = 0; nj < 8; ++nj)
#pragma unroll
                for (int r = 0; r < 4; ++r)
                    Pw[(mi * 16 + quad * 4 + r) * 136 + nj * 16 + col] = (bf16)sc[mi][nj][r];

        // O += P V   (kv=128 -> 4 mfma k-steps)
#pragma unroll
        for (int kk = 0; kk < 4; ++kk) {
            bf16x8 pa0 = *(const bf16x8*)(Pw + (col)      * 136 + kk * 32 + quad * 8);
            bf16x8 pa1 = *(const bf16x8*)(Pw + (16 + col) * 136 + kk * 32 + quad * 8);
#pragma unroll
            for (int jd = 0; jd < 4; ++jd) {
                bf16x8 vb = *(const bf16x8*)(Vt + (jd * 16 + col) * 136 + kk * 32 + quad * 8);
                of[0][jd] = __builtin_amdgcn_mfma_f32_16x16x32_bf16(pa0, vb, of[0][jd], 0, 0, 0);
                of[1][jd] = __builtin_amdgcn_mfma_f32_16x16x32_bf16(pa1, vb, of[1][jd], 0, 0, 0);
            }
        }
    }

    // normalize + write attn output (bf16) to [B,S,E]
#pragma unroll
    for (int mi = 0; mi < 2; ++mi)
#pragma unroll
        for (int r = 0; r < 4; ++r) {
            const int s = q0 + w * 32 + mi * 16 + quad * 4 + r;
            const float inv_l = 1.f / lrow[mi][r];
#pragma unroll
            for (int jd = 0; jd < 4; ++jd) {
                const int e = h * 64 + jd * 16 + col;
                O[((size_t)(b * 2048 + s)) * 1024 + e] = (bf16)(of[mi][jd][r] * inv_l);
            }
        }
}

// ---------------------------------------------------------------------------
// Output projection: out = attn @ Wo.T + bo.  attn is bf16 (ws); Wo, bo, out f32.
// ---------------------------------------------------------------------------
__global__ __launch_bounds__(256) void out_gemm(
    const bf16* __restrict__ A, const float* __restrict__ W,
    const float* __restrict__ bias, float* __restrict__ out)
{
    __shared__ alignas(16) bf16 As[128 * 40];
    __shared__ alignas(16) bf16 Bs[128 * 40];

    const int t    = threadIdx.x;
    const int lane = t & 63, w = t >> 6;
    const int quad = lane >> 4, col = lane & 15;
    const int n0 = blockIdx.x * 128;      // 0..7
    const int m0 = blockIdx.y * 128;      // 0..31
    const int K  = 1024;
    const int wm = (w >> 1) * 64, wn = (w & 1) * 64;
    const int r0 = t >> 2, c8 = (t & 3) * 8;
    f32x4 acc[4][4] = {};

    for (int k0 = 0; k0 < K; k0 += 32) {
        bf16x8 ax0 = *(const bf16x8*)(A + (size_t)(m0 + r0)      * K + k0 + c8);
        bf16x8 ax1 = *(const bf16x8*)(A + (size_t)(m0 + 64 + r0) * K + k0 + c8);
        bf16x8 bx0 = cvt8(W + (size_t)(n0 + r0)      * K + k0 + c8);
        bf16x8 bx1 = cvt8(W + (size_t)(n0 + 64 + r0) * K + k0 + c8);
        __syncthreads();
        *(bf16x8*)(As + r0 * 40 + c8)        = ax0;
        *(bf16x8*)(As + (64 + r0) * 40 + c8) = ax1;
        *(bf16x8*)(Bs + r0 * 40 + c8)        = bx0;
        *(bf16x8*)(Bs + (64 + r0) * 40 + c8) = bx1;
        __syncthreads();

        bf16x8 a[4], b[4];
#pragma unroll
        for (int i = 0; i < 4; ++i)
            a[i] = *(const bf16x8*)(As + (wm + i * 16 + col) * 40 + quad * 8);
#pragma unroll
        for (int j = 0; j < 4; ++j)
            b[j] = *(const bf16x8*)(Bs + (wn + j * 16 + col) * 40 + quad * 8);
#pragma unroll
        for (int i = 0; i < 4; ++i)
#pragma unroll
            for (int j = 0; j < 4; ++j)
                acc[i][j] = __builtin_amdgcn_mfma_f32_16x16x32_bf16(a[i], b[j], acc[i][j], 0, 0, 0);
    }

#pragma unroll
    for (int i = 0; i < 4; ++i) {
        const int mbase = m0 + wm + i * 16 + quad * 4;
#pragma unroll
        for (int j = 0; j < 4; ++j) {
            const int n = n0 + wn + j * 16 + col;
            const float bb = bias[n];
#pragma unroll
            for (int r = 0; r < 4; ++r)
                out[(size_t)(mbase + r) * 1024 + n] = acc[i][j][r] + bb;
        }
    }
}

extern "C" void kernel_launch(void* const* d_in, const int* in_sizes, int n_in,
                              void* d_out, int out_size, void* d_ws, size_t ws_size,
                              hipStream_t stream) {
    // Reference dtypes: ALL inputs and the output are float32.
    const float* x  = (const float*)d_in[0];
    const float* Wq = (const float*)d_in[1];
    const float* bq = (const float*)d_in[2];
    const float* Wk = (const float*)d_in[3];
    const float* bk = (const float*)d_in[4];
    const float* Wv = (const float*)d_in[5];
    const float* bv = (const float*)d_in[6];
    const float* Wo = (const float*)d_in[7];
    const float* bo = (const float*)d_in[8];
    float* out = (float*)d_out;

    // workspace: q,k,v in [B,H,S,D] + attn out in [B,S,E], all bf16 (32 MB)
    bf16* qws = (bf16*)d_ws;
    bf16* kws = qws + 4194304;
    bf16* vws = kws + 4194304;
    bf16* aws = vws + 4194304;

    qkv_gemm<<<dim3(24, 32), 256, 0, stream>>>(x, Wq, Wk, Wv, bq, bk, bv, qws, kws, vws);
    attn_kernel<<<dim3(512), 256, 0, stream>>>(qws, kws, vws, aws);
    out_gemm<<<dim3(8, 32), 256, 0, stream>>>(aws, Wo, bo, out);
}

// Round 5
// 240.388 us; speedup vs baseline: 1.0769x; 1.0769x over previous
//
#include <hip/hip_runtime.h>
#include <hip/hip_bf16.h>

typedef __bf16 bf16;
typedef __bf16 bf16x8 __attribute__((ext_vector_type(8)));
typedef float  f32x4  __attribute__((ext_vector_type(4)));

#define NEG_BIG (-1e30f)

#define AS1(p) ((const __attribute__((address_space(1))) void*)(p))
#define AS3(p) ((__attribute__((address_space(3))) void*)(p))

// async global->LDS, 16B/lane; dest = wave-uniform base + lane*16 (m104/m108)
__device__ __forceinline__ void stage16(const void* g, void* lds_uniform_base) {
    __builtin_amdgcn_global_load_lds(AS1(g), AS3(lds_uniform_base), 16, 0, 0);
}

// load 8 contiguous f32, round to bf16x8
__device__ __forceinline__ bf16x8 cvt8(const float* __restrict__ p) {
    bf16x8 r;
#pragma unroll
    for (int i = 0; i < 8; ++i) r[i] = (bf16)p[i];
    return r;
}

// ---------------------------------------------------------------------------
// x (f32, 4M elems) -> bf16 copy (one pass; 16+8 MB traffic ~ 4 us)
// ---------------------------------------------------------------------------
__global__ __launch_bounds__(256) void convert_x(const float* __restrict__ x,
                                                 bf16* __restrict__ xb) {
    const size_t i = ((size_t)blockIdx.x * 256 + threadIdx.x) * 8;
    *(bf16x8*)(xb + i) = cvt8(x + i);
}

// ---------------------------------------------------------------------------
// Fused QKV projection: y = xb @ W.T + b.  xb bf16 (A via global_load_lds),
// W/b f32 (B via cvt8 register staging).  Tile 128x128, BK=32.
// Epilogue scatters to [B,H,S,D]; Q gets *1/sqrt(D).
// ---------------------------------------------------------------------------
__global__ __launch_bounds__(256) void qkv_gemm(
    const bf16* __restrict__ Xb,
    const float* __restrict__ Wq, const float* __restrict__ Wk, const float* __restrict__ Wv,
    const float* __restrict__ bq, const float* __restrict__ bk, const float* __restrict__ bv,
    bf16* __restrict__ qo, bf16* __restrict__ ko, bf16* __restrict__ vo)
{
    __shared__ alignas(16) bf16 As[128 * 32];   // contiguous: global_load_lds layout
    __shared__ alignas(16) bf16 Bs[128 * 32];

    const int t    = threadIdx.x;
    const int lane = t & 63, w = t >> 6;
    const int quad = lane >> 4, col = lane & 15;
    const int nt = blockIdx.x;            // 0..23
    const int mt = blockIdx.y;            // 0..31
    const int region = nt >> 3;           // 0=q 1=k 2=v
    const int n0 = (nt & 7) * 128;
    const int m0 = mt * 128;
    const int K  = 1024;

    const float* W    = region == 0 ? Wq : (region == 1 ? Wk : Wv);
    const float* bias = region == 0 ? bq : (region == 1 ? bk : bv);
    bf16*        out  = region == 0 ? qo : (region == 1 ? ko : vo);
    const float scale = region == 0 ? 0.125f : 1.0f;

    const int wm = (w >> 1) * 64, wn = (w & 1) * 64;
    const int r0 = t >> 2, c8 = (t & 3) * 8;
    f32x4 acc[4][4] = {};

    for (int k0 = 0; k0 < K; k0 += 32) {
        // B tile: f32 -> bf16 register staging
        bf16x8 bx0 = cvt8(W + (size_t)(n0 + r0)      * K + k0 + c8);
        bf16x8 bx1 = cvt8(W + (size_t)(n0 + 64 + r0) * K + k0 + c8);
        __syncthreads();                  // prev iteration's LDS reads done
        // A tile: async 16B global->LDS (m97 pattern)
#pragma unroll
        for (int i = 0; i < 2; ++i) {     // chunk c: row=c>>2, kchunk=c&3
            int c = i * 256 + t;
            stage16(Xb + (size_t)(m0 + (c >> 2)) * K + k0 + (c & 3) * 8,
                    As + (i * 256 + w * 64) * 8);
        }
        *(bf16x8*)(Bs + r0 * 32 + c8)        = bx0;
        *(bf16x8*)(Bs + (64 + r0) * 32 + c8) = bx1;
        __syncthreads();                  // drains vmcnt (stage16) + lgkm

        bf16x8 a[4], b[4];
#pragma unroll
        for (int i = 0; i < 4; ++i)
            a[i] = *(const bf16x8*)(As + (wm + i * 16 + col) * 32 + quad * 8);
#pragma unroll
        for (int j = 0; j < 4; ++j)
            b[j] = *(const bf16x8*)(Bs + (wn + j * 16 + col) * 32 + quad * 8);
#pragma unroll
        for (int i = 0; i < 4; ++i)
#pragma unroll
            for (int j = 0; j < 4; ++j)
                acc[i][j] = __builtin_amdgcn_mfma_f32_16x16x32_bf16(a[i], b[j], acc[i][j], 0, 0, 0);
    }

    // C/D: col = lane&15, row = quad*4 + r
#pragma unroll
    for (int i = 0; i < 4; ++i) {
        const int mbase = m0 + wm + i * 16 + quad * 4;
#pragma unroll
        for (int j = 0; j < 4; ++j) {
            const int n = n0 + wn + j * 16 + col;
            const float bb = bias[n];
            const int h = n >> 6, d = n & 63;
#pragma unroll
            for (int r = 0; r < 4; ++r) {
                const int m  = mbase + r;
                const int b_ = m >> 11, s = m & 2047;
                out[(((size_t)(b_ * 16 + h)) * 2048 + s) * 64 + d] =
                    (bf16)((acc[i][j][r] + bb) * scale);
            }
        }
    }
}

// ---------------------------------------------------------------------------
// Flash attention with ALiBi + causal. One block = one (b,h) x 128-row Q tile.
// LDS: KP region unions Ks [128][72] with per-wave Ps [32][136] (barrier-
// separated); Vt [64][136]. Total 52.2 KB -> 2 blocks/CU resident.
// ---------------------------------------------------------------------------
__global__ __launch_bounds__(256) void attn_kernel(
    const bf16* __restrict__ Q, const bf16* __restrict__ Kg,
    const bf16* __restrict__ Vg, bf16* __restrict__ O)
{
    const int t    = threadIdx.x;
    const int lane = t & 63, w = t >> 6;
    const int quad = lane >> 4, col = lane & 15;
    const int bh = blockIdx.x & 31;
    const int qt = 15 - (blockIdx.x >> 5);    // biggest tiles dispatched first
    const int b  = bh >> 4, h = bh & 15;
    const int q0 = qt * 128;
    const float nslope = -exp2f(-0.5f * (float)(h + 1));

    const bf16* qp = Q  + (size_t)bh * 2048 * 64;
    const bf16* kp = Kg + (size_t)bh * 2048 * 64;
    const bf16* vp = Vg + (size_t)bh * 2048 * 64;

    __shared__ alignas(16) bf16 KP[4 * 32 * 136];   // Ks (9216) ∪ Ps (17408)
    __shared__ alignas(16) bf16 Vt[64 * 136];
    bf16* Ks = KP;
    bf16* Pw = KP + w * (32 * 136);

    bf16x8 qa[2][2];
#pragma unroll
    for (int mi = 0; mi < 2; ++mi)
#pragma unroll
        for (int ks = 0; ks < 2; ++ks)
            qa[mi][ks] = *(const bf16x8*)(qp + (size_t)(q0 + w * 32 + mi * 16 + col) * 64
                                          + ks * 32 + quad * 8);

    float mrow[2][4], lrow[2][4];
    f32x4 of[2][4] = {};
#pragma unroll
    for (int mi = 0; mi < 2; ++mi)
#pragma unroll
        for (int r = 0; r < 4; ++r) { mrow[mi][r] = NEG_BIG; lrow[mi][r] = 0.f; }

    for (int kvt = 0; kvt <= qt; ++kvt) {
        const int kv0 = kvt * 128;

        bf16x8 kx[4], va[2], vb_[2];
#pragma unroll
        for (int i = 0; i < 4; ++i) {
            int c = i * 256 + t;
            kx[i] = *(const bf16x8*)(kp + (size_t)(kv0 + (c >> 3)) * 64 + (c & 7) * 8);
        }
#pragma unroll
        for (int i = 0; i < 2; ++i) {
            int c = i * 256 + t;
            va[i]  = *(const bf16x8*)(vp + (size_t)(kv0 + (c >> 3) * 2)     * 64 + (c & 7) * 8);
            vb_[i] = *(const bf16x8*)(vp + (size_t)(kv0 + (c >> 3) * 2 + 1) * 64 + (c & 7) * 8);
        }
        __syncthreads();   // BARRIER1: all waves done with prev KP(Pw)/Vt reads
#pragma unroll
        for (int i = 0; i < 4; ++i) {
            int c = i * 256 + t;
            *(bf16x8*)(Ks + (c >> 3) * 72 + (c & 7) * 8) = kx[i];
        }
#pragma unroll
        for (int i = 0; i < 2; ++i) {
            int c = i * 256 + t;
            int kvp = c >> 3, dc = (c & 7) * 8;
#pragma unroll
            for (int e = 0; e < 8; ++e) {
                Vt[(dc + e) * 136 + kvp * 2]     = va[i][e];
                Vt[(dc + e) * 136 + kvp * 2 + 1] = vb_[i][e];
            }
        }
        __syncthreads();   // BARRIER2: Ks/Vt visible

        // S = Q K^T
        f32x4 sc[2][8];
#pragma unroll
        for (int nj = 0; nj < 8; ++nj) {
            bf16x8 k0f = *(const bf16x8*)(Ks + (nj * 16 + col) * 72 + quad * 8);
            bf16x8 k1f = *(const bf16x8*)(Ks + (nj * 16 + col) * 72 + 32 + quad * 8);
#pragma unroll
            for (int mi = 0; mi < 2; ++mi) {
                f32x4 z = {};
                z = __builtin_amdgcn_mfma_f32_16x16x32_bf16(qa[mi][0], k0f, z, 0, 0, 0);
                z = __builtin_amdgcn_mfma_f32_16x16x32_bf16(qa[mi][1], k1f, z, 0, 0, 0);
                sc[mi][nj] = z;
            }
        }

        const bool diag = (kvt == qt);
#pragma unroll
        for (int mi = 0; mi < 2; ++mi) {
#pragma unroll
            for (int r = 0; r < 4; ++r) {
                const int gi = q0 + w * 32 + mi * 16 + quad * 4 + r;
                float mx = NEG_BIG;
#pragma unroll
                for (int nj = 0; nj < 8; ++nj) {
                    const int gj = kv0 + nj * 16 + col;
                    float val = sc[mi][nj][r] + nslope * (float)(gi - gj);
                    if (diag && gj > gi) val = NEG_BIG;
                    sc[mi][nj][r] = val;
                    mx = fmaxf(mx, val);
                }
#pragma unroll
                for (int off = 1; off < 16; off <<= 1)
                    mx = fmaxf(mx, __shfl_xor(mx, off, 16));
                const float mo = mrow[mi][r];
                const float mn = fmaxf(mo, mx);
                const float alpha = __expf(mo - mn);
                float rs = 0.f;
#pragma unroll
                for (int nj = 0; nj < 8; ++nj) {
                    float p = __expf(sc[mi][nj][r] - mn);
                    sc[mi][nj][r] = p;
                    rs += p;
                }
#pragma unroll
                for (int off = 1; off < 16; off <<= 1)
                    rs += __shfl_xor(rs, off, 16);
                mrow[mi][r] = mn;
                lrow[mi][r] = lrow[mi][r] * alpha + rs;
#pragma unroll
                for (int jd = 0; jd < 4; ++jd) of[mi][jd][r] *= alpha;
            }
        }

        __syncthreads();   // BARRIER3: all waves done reading Ks before P overwrite

        // P: C/D -> A-operand layout via per-wave LDS region (aliases Ks)
#pragma unroll
        for (int mi = 0; mi < 2; ++mi)
#pragma unroll
            for (int nj = 0; nj < 8; ++nj)
#pragma unroll
                for (int r = 0; r < 4; ++r)
                    Pw[(mi * 16 + quad * 4 + r) * 136 + nj * 16 + col] = (bf16)sc[mi][nj][r];

        // O += P V
#pragma unroll
        for (int kk = 0; kk < 4; ++kk) {
            bf16x8 pa0 = *(const bf16x8*)(Pw + (col)      * 136 + kk * 32 + quad * 8);
            bf16x8 pa1 = *(const bf16x8*)(Pw + (16 + col) * 136 + kk * 32 + quad * 8);
#pragma unroll
            for (int jd = 0; jd < 4; ++jd) {
                bf16x8 vb = *(const bf16x8*)(Vt + (jd * 16 + col) * 136 + kk * 32 + quad * 8);
                of[0][jd] = __builtin_amdgcn_mfma_f32_16x16x32_bf16(pa0, vb, of[0][jd], 0, 0, 0);
                of[1][jd] = __builtin_amdgcn_mfma_f32_16x16x32_bf16(pa1, vb, of[1][jd], 0, 0, 0);
            }
        }
    }

    // normalize + write attn output (bf16) to [B,S,E]
#pragma unroll
    for (int mi = 0; mi < 2; ++mi)
#pragma unroll
        for (int r = 0; r < 4; ++r) {
            const int s = q0 + w * 32 + mi * 16 + quad * 4 + r;
            const float inv_l = 1.f / lrow[mi][r];
#pragma unroll
            for (int jd = 0; jd < 4; ++jd) {
                const int e = h * 64 + jd * 16 + col;
                O[((size_t)(b * 2048 + s)) * 1024 + e] = (bf16)(of[mi][jd][r] * inv_l);
            }
        }
}

// ---------------------------------------------------------------------------
// Output projection: out = attn @ Wo.T + bo.  A bf16 via stage16; W f32 cvt8.
// ---------------------------------------------------------------------------
__global__ __launch_bounds__(256) void out_gemm(
    const bf16* __restrict__ A, const float* __restrict__ W,
    const float* __restrict__ bias, float* __restrict__ out)
{
    __shared__ alignas(16) bf16 As[128 * 32];
    __shared__ alignas(16) bf16 Bs[128 * 32];

    const int t    = threadIdx.x;
    const int lane = t & 63, w = t >> 6;
    const int quad = lane >> 4, col = lane & 15;
    const int n0 = blockIdx.x * 128;
    const int m0 = blockIdx.y * 128;
    const int K  = 1024;
    const int wm = (w >> 1) * 64, wn = (w & 1) * 64;
    const int r0 = t >> 2, c8 = (t & 3) * 8;
    f32x4 acc[4][4] = {};

    for (int k0 = 0; k0 < K; k0 += 32) {
        bf16x8 bx0 = cvt8(W + (size_t)(n0 + r0)      * K + k0 + c8);
        bf16x8 bx1 = cvt8(W + (size_t)(n0 + 64 + r0) * K + k0 + c8);
        __syncthreads();
#pragma unroll
        for (int i = 0; i < 2; ++i) {
            int c = i * 256 + t;
            stage16(A + (size_t)(m0 + (c >> 2)) * K + k0 + (c & 3) * 8,
                    As + (i * 256 + w * 64) * 8);
        }
        *(bf16x8*)(Bs + r0 * 32 + c8)        = bx0;
        *(bf16x8*)(Bs + (64 + r0) * 32 + c8) = bx1;
        __syncthreads();

        bf16x8 a[4], b[4];
#pragma unroll
        for (int i = 0; i < 4; ++i)
            a[i] = *(const bf16x8*)(As + (wm + i * 16 + col) * 32 + quad * 8);
#pragma unroll
        for (int j = 0; j < 4; ++j)
            b[j] = *(const bf16x8*)(Bs + (wn + j * 16 + col) * 32 + quad * 8);
#pragma unroll
        for (int i = 0; i < 4; ++i)
#pragma unroll
            for (int j = 0; j < 4; ++j)
                acc[i][j] = __builtin_amdgcn_mfma_f32_16x16x32_bf16(a[i], b[j], acc[i][j], 0, 0, 0);
    }

#pragma unroll
    for (int i = 0; i < 4; ++i) {
        const int mbase = m0 + wm + i * 16 + quad * 4;
#pragma unroll
        for (int j = 0; j < 4; ++j) {
            const int n = n0 + wn + j * 16 + col;
            const float bb = bias[n];
#pragma unroll
            for (int r = 0; r < 4; ++r)
                out[(size_t)(mbase + r) * 1024 + n] = acc[i][j][r] + bb;
        }
    }
}

extern "C" void kernel_launch(void* const* d_in, const int* in_sizes, int n_in,
                              void* d_out, int out_size, void* d_ws, size_t ws_size,
                              hipStream_t stream) {
    const float* x  = (const float*)d_in[0];
    const float* Wq = (const float*)d_in[1];
    const float* bq = (const float*)d_in[2];
    const float* Wk = (const float*)d_in[3];
    const float* bk = (const float*)d_in[4];
    const float* Wv = (const float*)d_in[5];
    const float* bv = (const float*)d_in[6];
    const float* Wo = (const float*)d_in[7];
    const float* bo = (const float*)d_in[8];
    float* out = (float*)d_out;

    // ws (32 MB): [xb | q | k | v]; xb region is reused as attn output (aws)
    // after qkv_gemm has consumed it.
    bf16* xb  = (bf16*)d_ws;               // 4M elems (8 MB) — later: attn out
    bf16* qws = xb  + 4194304;
    bf16* kws = qws + 4194304;
    bf16* vws = kws + 4194304;
    bf16* aws = xb;                        // alias: attn writes after qkv reads

    convert_x<<<dim3(2048), 256, 0, stream>>>(x, xb);
    qkv_gemm <<<dim3(24, 32), 256, 0, stream>>>(xb, Wq, Wk, Wv, bq, bk, bv, qws, kws, vws);
    attn_kernel<<<dim3(512), 256, 0, stream>>>(qws, kws, vws, aws);
    out_gemm <<<dim3(8, 32), 256, 0, stream>>>(aws, Wo, bo, out);
}

// Round 7
// 237.748 us; speedup vs baseline: 1.0889x; 1.0111x over previous
//
#include <hip/hip_runtime.h>
#include <hip/hip_bf16.h>

typedef __bf16 bf16;
typedef __bf16 bf16x8 __attribute__((ext_vector_type(8)));
typedef float  f32x4  __attribute__((ext_vector_type(4)));

#define NEG_BIG (-1e30f)

#define AS1(p) ((const __attribute__((address_space(1))) void*)(p))
#define AS3(p) ((__attribute__((address_space(3))) void*)(p))

// async global->LDS, 16B/lane; dest = wave-uniform base + lane*16 (m104/m108)
__device__ __forceinline__ void stage16(const void* g, void* lds_uniform_base) {
    __builtin_amdgcn_global_load_lds(AS1(g), AS3(lds_uniform_base), 16, 0, 0);
}

__device__ __forceinline__ bf16x8 cvt8(const float* __restrict__ p) {
    bf16x8 r;
#pragma unroll
    for (int i = 0; i < 8; ++i) r[i] = (bf16)p[i];
    return r;
}

// ---------------------------------------------------------------------------
// One-pass f32->bf16 conversions: x -> xb (ws), Wq/Wk/Wv -> wb (d_out scratch).
// ---------------------------------------------------------------------------
__global__ __launch_bounds__(256) void conv_all(
    const float* __restrict__ x,  const float* __restrict__ wq,
    const float* __restrict__ wk, const float* __restrict__ wv,
    bf16* __restrict__ xb, bf16* __restrict__ wb)
{
    const int blk = blockIdx.x;
    const float* src; bf16* dst; size_t off;
    if (blk < 2048)      { src = x;  dst = xb;           off = (size_t)blk * 2048; }
    else if (blk < 2560) { src = wq; dst = wb;           off = (size_t)(blk - 2048) * 2048; }
    else if (blk < 3072) { src = wk; dst = wb + 1048576; off = (size_t)(blk - 2560) * 2048; }
    else                 { src = wv; dst = wb + 2097152; off = (size_t)(blk - 3072) * 2048; }
    const size_t i = off + (size_t)threadIdx.x * 8;
    *(bf16x8*)(dst + i) = cvt8(src + i);
}

// ---------------------------------------------------------------------------
// Fused QKV projection, all-bf16 (m97 structure: stage16 both operands).
// y = xb @ Wb.T + b; epilogue scatters to [B,H,S,D]. Q gets *1/8 (e-base attn).
// ---------------------------------------------------------------------------
__global__ __launch_bounds__(256) void qkv_gemm(
    const bf16* __restrict__ Xb, const bf16* __restrict__ Wb,
    const float* __restrict__ bq, const float* __restrict__ bk, const float* __restrict__ bv,
    bf16* __restrict__ qo, bf16* __restrict__ ko, bf16* __restrict__ vo)
{
    __shared__ alignas(16) bf16 As[128 * 32];
    __shared__ alignas(16) bf16 Bs[128 * 32];

    const int t    = threadIdx.x;
    const int lane = t & 63, w = t >> 6;
    const int quad = lane >> 4, col = lane & 15;
    const int nt = blockIdx.x;            // 0..23
    const int mt = blockIdx.y;            // 0..31
    const int region = nt >> 3;           // 0=q 1=k 2=v
    const int n0 = (nt & 7) * 128;
    const int m0 = mt * 128;
    const int K  = 1024;

    const bf16*  W    = Wb + (size_t)region * 1048576;
    const float* bias = region == 0 ? bq : (region == 1 ? bk : bv);
    bf16*        out  = region == 0 ? qo : (region == 1 ? ko : vo);
    const float scale = region == 0 ? 0.125f : 1.0f;   // e-base downstream

    const int wm = (w >> 1) * 64, wn = (w & 1) * 64;
    f32x4 acc[4][4] = {};

    for (int k0 = 0; k0 < K; k0 += 32) {
        __syncthreads();                  // prev iteration's LDS reads done
#pragma unroll
        for (int i = 0; i < 2; ++i) {     // chunk c: row=c>>2, kchunk=c&3
            int c = i * 256 + t;
            stage16(Xb + (size_t)(m0 + (c >> 2)) * K + k0 + (c & 3) * 8,
                    As + (i * 256 + w * 64) * 8);
        }
#pragma unroll
        for (int i = 0; i < 2; ++i) {
            int c = i * 256 + t;
            stage16(W + (size_t)(n0 + (c >> 2)) * K + k0 + (c & 3) * 8,
                    Bs + (i * 256 + w * 64) * 8);
        }
        __syncthreads();                  // drains vmcnt

        bf16x8 a[4], b[4];
#pragma unroll
        for (int i = 0; i < 4; ++i)
            a[i] = *(const bf16x8*)(As + (wm + i * 16 + col) * 32 + quad * 8);
#pragma unroll
        for (int j = 0; j < 4; ++j)
            b[j] = *(const bf16x8*)(Bs + (wn + j * 16 + col) * 32 + quad * 8);
#pragma unroll
        for (int i = 0; i < 4; ++i)
#pragma unroll
            for (int j = 0; j < 4; ++j)
                acc[i][j] = __builtin_amdgcn_mfma_f32_16x16x32_bf16(a[i], b[j], acc[i][j], 0, 0, 0);
    }

    // C/D: col = lane&15, row = quad*4 + r
#pragma unroll
    for (int i = 0; i < 4; ++i) {
        const int mbase = m0 + wm + i * 16 + quad * 4;
#pragma unroll
        for (int j = 0; j < 4; ++j) {
            const int n = n0 + wn + j * 16 + col;
            const float bb = bias[n];
            const int h = n >> 6, d = n & 63;
#pragma unroll
            for (int r = 0; r < 4; ++r) {
                const int m  = mbase + r;
                const int b_ = m >> 11, s = m & 2047;
                out[(((size_t)(b_ * 16 + h)) * 2048 + s) * 64 + d] =
                    (bf16)((acc[i][j][r] + bb) * scale);
            }
        }
    }
}

// ---------------------------------------------------------------------------
// Flash attention (ROUND-5 EXACT — proven). ALiBi + causal, online softmax.
// One block = one (b,h) x 128-row Q tile. Ks ∪ Ps union, Vt transposed.
// ---------------------------------------------------------------------------
__global__ __launch_bounds__(256) void attn_kernel(
    const bf16* __restrict__ Q, const bf16* __restrict__ Kg,
    const bf16* __restrict__ Vg, bf16* __restrict__ O)
{
    const int t    = threadIdx.x;
    const int lane = t & 63, w = t >> 6;
    const int quad = lane >> 4, col = lane & 15;
    const int bh = blockIdx.x & 31;
    const int qt = 15 - (blockIdx.x >> 5);    // biggest tiles dispatched first
    const int b  = bh >> 4, h = bh & 15;
    const int q0 = qt * 128;
    const float nslope = -exp2f(-0.5f * (float)(h + 1));

    const bf16* qp = Q  + (size_t)bh * 2048 * 64;
    const bf16* kp = Kg + (size_t)bh * 2048 * 64;
    const bf16* vp = Vg + (size_t)bh * 2048 * 64;

    __shared__ alignas(16) bf16 KP[4 * 32 * 136];   // Ks (9216) ∪ Ps (17408)
    __shared__ alignas(16) bf16 Vt[64 * 136];
    bf16* Ks = KP;
    bf16* Pw = KP + w * (32 * 136);

    bf16x8 qa[2][2];
#pragma unroll
    for (int mi = 0; mi < 2; ++mi)
#pragma unroll
        for (int ks = 0; ks < 2; ++ks)
            qa[mi][ks] = *(const bf16x8*)(qp + (size_t)(q0 + w * 32 + mi * 16 + col) * 64
                                          + ks * 32 + quad * 8);

    float mrow[2][4], lrow[2][4];
    f32x4 of[2][4] = {};
#pragma unroll
    for (int mi = 0; mi < 2; ++mi)
#pragma unroll
        for (int r = 0; r < 4; ++r) { mrow[mi][r] = NEG_BIG; lrow[mi][r] = 0.f; }

    for (int kvt = 0; kvt <= qt; ++kvt) {
        const int kv0 = kvt * 128;

        bf16x8 kx[4], va[2], vb_[2];
#pragma unroll
        for (int i = 0; i < 4; ++i) {
            int c = i * 256 + t;
            kx[i] = *(const bf16x8*)(kp + (size_t)(kv0 + (c >> 3)) * 64 + (c & 7) * 8);
        }
#pragma unroll
        for (int i = 0; i < 2; ++i) {
            int c = i * 256 + t;
            va[i]  = *(const bf16x8*)(vp + (size_t)(kv0 + (c >> 3) * 2)     * 64 + (c & 7) * 8);
            vb_[i] = *(const bf16x8*)(vp + (size_t)(kv0 + (c >> 3) * 2 + 1) * 64 + (c & 7) * 8);
        }
        __syncthreads();   // BARRIER1: all waves done with prev KP(Pw)/Vt reads
#pragma unroll
        for (int i = 0; i < 4; ++i) {
            int c = i * 256 + t;
            *(bf16x8*)(Ks + (c >> 3) * 72 + (c & 7) * 8) = kx[i];
        }
#pragma unroll
        for (int i = 0; i < 2; ++i) {
            int c = i * 256 + t;
            int kvp = c >> 3, dc = (c & 7) * 8;
#pragma unroll
            for (int e = 0; e < 8; ++e) {
                Vt[(dc + e) * 136 + kvp * 2]     = va[i][e];
                Vt[(dc + e) * 136 + kvp * 2 + 1] = vb_[i][e];
            }
        }
        __syncthreads();   // BARRIER2: Ks/Vt visible

        // S = Q K^T
        f32x4 sc[2][8];
#pragma unroll
        for (int nj = 0; nj < 8; ++nj) {
            bf16x8 k0f = *(const bf16x8*)(Ks + (nj * 16 + col) * 72 + quad * 8);
            bf16x8 k1f = *(const bf16x8*)(Ks + (nj * 16 + col) * 72 + 32 + quad * 8);
#pragma unroll
            for (int mi = 0; mi < 2; ++mi) {
                f32x4 z = {};
                z = __builtin_amdgcn_mfma_f32_16x16x32_bf16(qa[mi][0], k0f, z, 0, 0, 0);
                z = __builtin_amdgcn_mfma_f32_16x16x32_bf16(qa[mi][1], k1f, z, 0, 0, 0);
                sc[mi][nj] = z;
            }
        }

        const bool diag = (kvt == qt);
#pragma unroll
        for (int mi = 0; mi < 2; ++mi) {
#pragma unroll
            for (int r = 0; r < 4; ++r) {
                const int gi = q0 + w * 32 + mi * 16 + quad * 4 + r;
                float mx = NEG_BIG;
#pragma unroll
                for (int nj = 0; nj < 8; ++nj) {
                    const int gj = kv0 + nj * 16 + col;
                    float val = sc[mi][nj][r] + nslope * (float)(gi - gj);
                    if (diag && gj > gi) val = NEG_BIG;
                    sc[mi][nj][r] = val;
                    mx = fmaxf(mx, val);
                }
#pragma unroll
                for (int off = 1; off < 16; off <<= 1)
                    mx = fmaxf(mx, __shfl_xor(mx, off, 16));
                const float mo = mrow[mi][r];
                const float mn = fmaxf(mo, mx);
                const float alpha = __expf(mo - mn);
                float rs = 0.f;
#pragma unroll
                for (int nj = 0; nj < 8; ++nj) {
                    float p = __expf(sc[mi][nj][r] - mn);
                    sc[mi][nj][r] = p;
                    rs += p;
                }
#pragma unroll
                for (int off = 1; off < 16; off <<= 1)
                    rs += __shfl_xor(rs, off, 16);
                mrow[mi][r] = mn;
                lrow[mi][r] = lrow[mi][r] * alpha + rs;
#pragma unroll
                for (int jd = 0; jd < 4; ++jd) of[mi][jd][r] *= alpha;
            }
        }

        __syncthreads();   // BARRIER3: all waves done reading Ks before P overwrite

        // P: C/D -> A-operand layout via per-wave LDS region (aliases Ks)
#pragma unroll
        for (int mi = 0; mi < 2; ++mi)
#pragma unroll
            for (int nj = 0; nj < 8; ++nj)
#pragma unroll
                for (int r = 0; r < 4; ++r)
                    Pw[(mi * 16 + quad * 4 + r) * 136 + nj * 16 + col] = (bf16)sc[mi][nj][r];

        // O += P V
#pragma unroll
        for (int kk = 0; kk < 4; ++kk) {
            bf16x8 pa0 = *(const bf16x8*)(Pw + (col)      * 136 + kk * 32 + quad * 8);
            bf16x8 pa1 = *(const bf16x8*)(Pw + (16 + col) * 136 + kk * 32 + quad * 8);
#pragma unroll
            for (int jd = 0; jd < 4; ++jd) {
                bf16x8 vbf = *(const bf16x8*)(Vt + (jd * 16 + col) * 136 + kk * 32 + quad * 8);
                of[0][jd] = __builtin_amdgcn_mfma_f32_16x16x32_bf16(pa0, vbf, of[0][jd], 0, 0, 0);
                of[1][jd] = __builtin_amdgcn_mfma_f32_16x16x32_bf16(pa1, vbf, of[1][jd], 0, 0, 0);
            }
        }
    }

    // normalize + write attn output (bf16) to [B,S,E]
#pragma unroll
    for (int mi = 0; mi < 2; ++mi)
#pragma unroll
        for (int r = 0; r < 4; ++r) {
            const int s = q0 + w * 32 + mi * 16 + quad * 4 + r;
            const float inv_l = 1.f / lrow[mi][r];
#pragma unroll
            for (int jd = 0; jd < 4; ++jd) {
                const int e = h * 64 + jd * 16 + col;
                O[((size_t)(b * 2048 + s)) * 1024 + e] = (bf16)(of[mi][jd][r] * inv_l);
            }
        }
}

// ---------------------------------------------------------------------------
// Output projection: out = attn @ Wo.T + bo.  A bf16 via stage16; Wo f32 cvt8.
// ---------------------------------------------------------------------------
__global__ __launch_bounds__(256) void out_gemm(
    const bf16* __restrict__ A, const float* __restrict__ W,
    const float* __restrict__ bias, float* __restrict__ out)
{
    __shared__ alignas(16) bf16 As[128 * 32];
    __shared__ alignas(16) bf16 Bs[128 * 32];

    const int t    = threadIdx.x;
    const int lane = t & 63, w = t >> 6;
    const int quad = lane >> 4, col = lane & 15;
    const int n0 = blockIdx.x * 128;
    const int m0 = blockIdx.y * 128;
    const int K  = 1024;
    const int wm = (w >> 1) * 64, wn = (w & 1) * 64;
    const int r0 = t >> 2, c8 = (t & 3) * 8;
    f32x4 acc[4][4] = {};

    for (int k0 = 0; k0 < K; k0 += 32) {
        bf16x8 bx0 = cvt8(W + (size_t)(n0 + r0)      * K + k0 + c8);
        bf16x8 bx1 = cvt8(W + (size_t)(n0 + 64 + r0) * K + k0 + c8);
        __syncthreads();
#pragma unroll
        for (int i = 0; i < 2; ++i) {
            int c = i * 256 + t;
            stage16(A + (size_t)(m0 + (c >> 2)) * K + k0 + (c & 3) * 8,
                    As + (i * 256 + w * 64) * 8);
        }
        *(bf16x8*)(Bs + r0 * 32 + c8)        = bx0;
        *(bf16x8*)(Bs + (64 + r0) * 32 + c8) = bx1;
        __syncthreads();

        bf16x8 a[4], b[4];
#pragma unroll
        for (int i = 0; i < 4; ++i)
            a[i] = *(const bf16x8*)(As + (wm + i * 16 + col) * 32 + quad * 8);
#pragma unroll
        for (int j = 0; j < 4; ++j)
            b[j] = *(const bf16x8*)(Bs + (wn + j * 16 + col) * 32 + quad * 8);
#pragma unroll
        for (int i = 0; i < 4; ++i)
#pragma unroll
            for (int j = 0; j < 4; ++j)
                acc[i][j] = __builtin_amdgcn_mfma_f32_16x16x32_bf16(a[i], b[j], acc[i][j], 0, 0, 0);
    }

#pragma unroll
    for (int i = 0; i < 4; ++i) {
        const int mbase = m0 + wm + i * 16 + quad * 4;
#pragma unroll
        for (int j = 0; j < 4; ++j) {
            const int n = n0 + wn + j * 16 + col;
            const float bb = bias[n];
#pragma unroll
            for (int r = 0; r < 4; ++r)
                out[(size_t)(mbase + r) * 1024 + n] = acc[i][j][r] + bb;
        }
    }
}

extern "C" void kernel_launch(void* const* d_in, const int* in_sizes, int n_in,
                              void* d_out, int out_size, void* d_ws, size_t ws_size,
                              hipStream_t stream) {
    const float* x  = (const float*)d_in[0];
    const float* Wq = (const float*)d_in[1];
    const float* bq = (const float*)d_in[2];
    const float* Wk = (const float*)d_in[3];
    const float* bk = (const float*)d_in[4];
    const float* Wv = (const float*)d_in[5];
    const float* bv = (const float*)d_in[6];
    const float* Wo = (const float*)d_in[7];
    const float* bo = (const float*)d_in[8];
    float* out = (float*)d_out;

    // ws (32 MB, proven): [xb | q | k | v] bf16; attn output aliases xb.
    bf16* xb  = (bf16*)d_ws;
    bf16* qws = xb  + 4194304;
    bf16* kws = qws + 4194304;
    bf16* vws = kws + 4194304;
    bf16* aws = xb;

    // d_out doubles as scratch for bf16 Wq/Wk/Wv (6 MB of its 16.8 MB);
    // fully overwritten by out_gemm at the end.
    bf16* wb = (bf16*)d_out;

    conv_all<<<dim3(3584), 256, 0, stream>>>(x, Wq, Wk, Wv, xb, wb);
    qkv_gemm<<<dim3(24, 32), 256, 0, stream>>>(xb, wb, bq, bk, bv, qws, kws, vws);
    attn_kernel<<<dim3(512), 256, 0, stream>>>(qws, kws, vws, aws);
    out_gemm<<<dim3(8, 32), 256, 0, stream>>>(aws, Wo, bo, out);
}